// Round 2
// baseline (431.188 us; speedup 1.0000x reference)
//
#include <hip/hip_runtime.h>
#include <stdint.h>

typedef unsigned short u16;
typedef short bf16x8 __attribute__((ext_vector_type(8)));
typedef float f32x4 __attribute__((ext_vector_type(4)));

#define B_   4
#define S_   2048
#define D_   1024
#define ND3  3072

// RNE float->bf16
__device__ __forceinline__ u16 f2bf(float x) {
    union { float f; uint32_t u; } v; v.f = x;
    uint32_t r = v.u + 0x7fffu + ((v.u >> 16) & 1u);
    return (u16)(r >> 16);
}
__device__ __forceinline__ float bf2f(u16 h) {
    union { uint32_t u; float f; } v; v.u = ((uint32_t)h) << 16;
    return v.f;
}

__device__ __forceinline__ void gload_lds16(const u16* g, u16* l) {
    __builtin_amdgcn_global_load_lds((const __attribute__((address_space(1))) void*)g,
                                     (__attribute__((address_space(3))) void*)l, 16, 0, 0);
}

// ---------------- core 128x128 bf16 GEMM tile (A [M][K] rm, Bt [N][K] rm) ----------------
// 256 threads = 4 waves (2x2), each wave 64x64 = 4x4 fragments of 16x16x32 MFMA.
// Accumulates into acc (callable repeatedly for K-segmented hi/lo GEMMs).
__device__ __forceinline__ void gemm_tile_bt(
    const u16* __restrict__ A, int lda,
    const u16* __restrict__ Bt, int ldb,
    int K, int rowbase, int colbase,
    u16* As, u16* Bs, f32x4 (&acc)[4][4])
{
    const int tid  = threadIdx.x;
    const int lane = tid & 63;
    const int w    = tid >> 6;
    const int wu   = __builtin_amdgcn_readfirstlane(w);
    const int wr   = w >> 1, wc = w & 1;

    // staging: each 1024B LDS block = 16 rows x 32 bf16; lane l -> row l/4, col (l&3)*8
    const int srow = lane >> 2;
    const int scol = (lane & 3) << 3;

    const u16* Ag = A  + (size_t)(rowbase + wu * 16 + srow) * lda + scol;
    const u16* Bg = Bt + (size_t)(colbase + wu * 16 + srow) * ldb + scol;
    u16* AsW = As + wu * 512;   // wave handles row-blocks wu and wu+4
    u16* BsW = Bs + wu * 512;

    const int aoff = (lane >> 4) << 3;       // k-chunk of 8 contiguous
    const int ar   = wr * 64 + (lane & 15);  // A fragment row
    const int br   = wc * 64 + (lane & 15);  // B fragment col (= Bt row)

    for (int kt = 0; kt < K; kt += 32) {
        gload_lds16(Ag + kt,                    AsW);
        gload_lds16(Ag + kt + (size_t)64 * lda, AsW + 2048);
        gload_lds16(Bg + kt,                    BsW);
        gload_lds16(Bg + kt + (size_t)64 * ldb, BsW + 2048);
        __syncthreads();
        bf16x8 af[4], bfr[4];
#pragma unroll
        for (int m = 0; m < 4; ++m)
            af[m] = *(const bf16x8*)(As + (ar + m * 16) * 32 + aoff);
#pragma unroll
        for (int n = 0; n < 4; ++n)
            bfr[n] = *(const bf16x8*)(Bs + (br + n * 16) * 32 + aoff);
#pragma unroll
        for (int m = 0; m < 4; ++m)
#pragma unroll
            for (int n = 0; n < 4; ++n)
                acc[m][n] = __builtin_amdgcn_mfma_f32_16x16x32_bf16(af[m], bfr[n], acc[m][n], 0, 0, 0);
        __syncthreads();
    }
}

// ---------------- stage 0a: fp32 -> (hi, lo) bf16 split ----------------
__global__ __launch_bounds__(256) void k_split_f32(const float* __restrict__ in,
                                                   u16* __restrict__ oh,
                                                   u16* __restrict__ ol, int n) {
    int i = (blockIdx.x * 256 + threadIdx.x) << 3;
    if (i >= n) return;
    float4 a = *(const float4*)(in + i);
    float4 b = *(const float4*)(in + i + 4);
    ushort4 h0, h1, l0, l1;
    h0.x = f2bf(a.x); l0.x = f2bf(a.x - bf2f(h0.x));
    h0.y = f2bf(a.y); l0.y = f2bf(a.y - bf2f(h0.y));
    h0.z = f2bf(a.z); l0.z = f2bf(a.z - bf2f(h0.z));
    h0.w = f2bf(a.w); l0.w = f2bf(a.w - bf2f(h0.w));
    h1.x = f2bf(b.x); l1.x = f2bf(b.x - bf2f(h1.x));
    h1.y = f2bf(b.y); l1.y = f2bf(b.y - bf2f(h1.y));
    h1.z = f2bf(b.z); l1.z = f2bf(b.z - bf2f(h1.z));
    h1.w = f2bf(b.w); l1.w = f2bf(b.w - bf2f(h1.w));
    *(ushort4*)(oh + i)     = h0;
    *(ushort4*)(oh + i + 4) = h1;
    *(ushort4*)(ol + i)     = l0;
    *(ushort4*)(ol + i + 4) = l1;
}

// ---------------- stage 0b: W [R][C] fp32 -> Wt hi/lo [C][R] bf16 ----------------
__global__ __launch_bounds__(256) void k_transpose_split(const float* __restrict__ W,
                                                         u16* __restrict__ Wth,
                                                         u16* __restrict__ Wtl, int R, int C) {
    __shared__ float t[32][33];
    int tx = threadIdx.x & 31, ty = threadIdx.x >> 5;
    int c0 = blockIdx.x << 5, r0 = blockIdx.y << 5;
#pragma unroll
    for (int i = 0; i < 4; ++i) {
        int r = (i << 3) + ty;
        t[r][tx] = W[(size_t)(r0 + r) * C + c0 + tx];
    }
    __syncthreads();
#pragma unroll
    for (int i = 0; i < 4; ++i) {
        int r = (i << 3) + ty;
        float w = t[tx][r];
        u16 h = f2bf(w);
        Wth[(size_t)(c0 + r) * R + r0 + tx] = h;
        Wtl[(size_t)(c0 + r) * R + r0 + tx] = f2bf(w - bf2f(h));
    }
}

// ---------------- stage 1: QKV = x @ W + b (hi/lo 3-segment); split-store q,k; v transposed ----------------
__global__ __launch_bounds__(256) void k_qkv(const u16* __restrict__ xh,
                                             const u16* __restrict__ xl,
                                             const u16* __restrict__ wth,
                                             const u16* __restrict__ wtl,
                                             const float* __restrict__ bias,
                                             u16* __restrict__ qh, u16* __restrict__ ql,
                                             u16* __restrict__ kh, u16* __restrict__ kl,
                                             u16* __restrict__ vt) {
    __shared__ u16 As[4096], Bs[4096];
    f32x4 acc[4][4];
    f32x4 z = {0.f, 0.f, 0.f, 0.f};
#pragma unroll
    for (int m = 0; m < 4; ++m)
#pragma unroll
        for (int n = 0; n < 4; ++n) acc[m][n] = z;

    const int rowbase = blockIdx.y << 7;
    const int colbase = blockIdx.x << 7;
    gemm_tile_bt(xh, D_, wth, D_, D_, rowbase, colbase, As, Bs, acc);
    gemm_tile_bt(xh, D_, wtl, D_, D_, rowbase, colbase, As, Bs, acc);
    gemm_tile_bt(xl, D_, wth, D_, D_, rowbase, colbase, As, Bs, acc);

    const int lane = threadIdx.x & 63;
    const int w = threadIdx.x >> 6;
    const int wr = w >> 1, wc = w & 1;
    const int region = colbase >> 10;   // 0=q, 1=k, 2=v (BN=128 divides 1024)
#pragma unroll
    for (int m = 0; m < 4; ++m) {
        int gr0 = rowbase + wr * 64 + m * 16 + ((lane >> 4) << 2);
#pragma unroll
        for (int n = 0; n < 4; ++n) {
            int gc = colbase + wc * 64 + n * 16 + (lane & 15);
            float bv = bias[gc];
            if (region == 0) {
#pragma unroll
                for (int r = 0; r < 4; ++r) {
                    float val = acc[m][n][r] + bv;
                    u16 h = f2bf(val);
                    size_t idx = (size_t)(gr0 + r) * D_ + gc;
                    qh[idx] = h;
                    ql[idx] = f2bf(val - bf2f(h));
                }
            } else if (region == 1) {
                int c = gc - 1024;
#pragma unroll
                for (int r = 0; r < 4; ++r) {
                    float val = acc[m][n][r] + bv;
                    u16 h = f2bf(val);
                    size_t idx = (size_t)(gr0 + r) * D_ + c;
                    kh[idx] = h;
                    kl[idx] = f2bf(val - bf2f(h));
                }
            } else {
                int d  = gc - 2048;
                int b  = gr0 >> 11;
                int t0 = gr0 & 2047;
                size_t base = (((size_t)b << 10) + d) * (size_t)S_ + t0;
#pragma unroll
                for (int r = 0; r < 4; ++r)
                    vt[base + r] = f2bf(acc[m][n][r] + bv);
            }
        }
    }
}

// ---------------- stage 2: attn = sigmoid(32 * q @ k^T) (hi/lo 3-segment), bf16 ----------------
__global__ __launch_bounds__(256) void k_scores(const u16* __restrict__ qh,
                                                const u16* __restrict__ ql,
                                                const u16* __restrict__ kh,
                                                const u16* __restrict__ kl,
                                                u16* __restrict__ attn) {
    __shared__ u16 As[4096], Bs[4096];
    f32x4 acc[4][4];
    f32x4 z = {0.f, 0.f, 0.f, 0.f};
#pragma unroll
    for (int m = 0; m < 4; ++m)
#pragma unroll
        for (int n = 0; n < 4; ++n) acc[m][n] = z;

    const int b = blockIdx.z;
    const size_t boff = (size_t)b * S_ * D_;
    u16* att = attn + (size_t)b * S_ * S_;
    const int rowbase = blockIdx.y << 7, colbase = blockIdx.x << 7;
    gemm_tile_bt(qh + boff, D_, kh + boff, D_, D_, rowbase, colbase, As, Bs, acc);
    gemm_tile_bt(qh + boff, D_, kl + boff, D_, D_, rowbase, colbase, As, Bs, acc);
    gemm_tile_bt(ql + boff, D_, kh + boff, D_, D_, rowbase, colbase, As, Bs, acc);

    const int lane = threadIdx.x & 63;
    const int w = threadIdx.x >> 6;
    const int wr = w >> 1, wc = w & 1;
#pragma unroll
    for (int m = 0; m < 4; ++m) {
        int gr0 = rowbase + wr * 64 + m * 16 + ((lane >> 4) << 2);
#pragma unroll
        for (int n = 0; n < 4; ++n) {
            int gc = colbase + wc * 64 + n * 16 + (lane & 15);
#pragma unroll
            for (int r = 0; r < 4; ++r) {
                float sv = acc[m][n][r] * 32.0f;   // scores / D^-0.5
                float sg = 1.0f / (1.0f + __expf(-sv));
                att[(size_t)(gr0 + r) * S_ + gc] = f2bf(sg);
            }
        }
    }
}

// ---------------- stage 3: out = attn @ v  (Bt = v^T [D][S]) ----------------
__global__ __launch_bounds__(256) void k_pv(const u16* __restrict__ attn,
                                            const u16* __restrict__ vt,
                                            float* __restrict__ out) {
    __shared__ u16 As[4096], Bs[4096];
    f32x4 acc[4][4];
    f32x4 z = {0.f, 0.f, 0.f, 0.f};
#pragma unroll
    for (int m = 0; m < 4; ++m)
#pragma unroll
        for (int n = 0; n < 4; ++n) acc[m][n] = z;

    const int b = blockIdx.z;
    const u16* Aa = attn + (size_t)b * S_ * S_;
    const u16* Bv = vt   + (size_t)b * D_ * S_;
    float* ob     = out  + (size_t)b * S_ * D_;
    const int rowbase = blockIdx.y << 7, colbase = blockIdx.x << 7;
    gemm_tile_bt(Aa, S_, Bv, S_, S_, rowbase, colbase, As, Bs, acc);

    const int lane = threadIdx.x & 63;
    const int w = threadIdx.x >> 6;
    const int wr = w >> 1, wc = w & 1;
#pragma unroll
    for (int m = 0; m < 4; ++m) {
        int gr0 = rowbase + wr * 64 + m * 16 + ((lane >> 4) << 2);
#pragma unroll
        for (int n = 0; n < 4; ++n) {
            int gc = colbase + wc * 64 + n * 16 + (lane & 15);
#pragma unroll
            for (int r = 0; r < 4; ++r)
                ob[(size_t)(gr0 + r) * D_ + gc] = acc[m][n][r];
        }
    }
}

extern "C" void kernel_launch(void* const* d_in, const int* in_sizes, int n_in,
                              void* d_out, int out_size, void* d_ws, size_t ws_size,
                              hipStream_t stream) {
    const float* x    = (const float*)d_in[0];
    const float* wqkv = (const float*)d_in[1];
    const float* bias = (const float*)d_in[2];
    float* out = (float*)d_out;

    const size_t MB = 1048576;
    uint8_t* ws = (uint8_t*)d_ws;
    u16* xh   = (u16*)(ws);              // [8192][1024] bf16   16 MB
    u16* xl   = (u16*)(ws + 16 * MB);    // 16 MB
    u16* wth  = (u16*)(ws + 32 * MB);    // [3072][1024] bf16    6 MB
    u16* wtl  = (u16*)(ws + 38 * MB);    //  6 MB
    u16* qh   = (u16*)(ws + 44 * MB);    // [B][S][D] bf16      16 MB
    u16* ql   = (u16*)(ws + 60 * MB);    // 16 MB
    u16* kh   = (u16*)(ws + 76 * MB);    // 16 MB
    u16* kl   = (u16*)(ws + 92 * MB);    // 16 MB
    u16* vt   = (u16*)(ws + 108 * MB);   // [B][D][S] bf16      16 MB (ends 124 MB)
    u16* attn = (u16*)(ws);              // [B][S][S] bf16 32 MB — aliases xh/xl (dead after QKV)

    k_split_f32<<<dim3(4096), dim3(256), 0, stream>>>(x, xh, xl, B_ * S_ * D_);
    k_transpose_split<<<dim3(ND3 / 32, D_ / 32), dim3(256), 0, stream>>>(wqkv, wth, wtl, D_, ND3);
    k_qkv<<<dim3(ND3 / 128, (B_ * S_) / 128), dim3(256), 0, stream>>>(xh, xl, wth, wtl, bias,
                                                                      qh, ql, kh, kl, vt);
    k_scores<<<dim3(S_ / 128, S_ / 128, B_), dim3(256), 0, stream>>>(qh, ql, kh, kl, attn);
    k_pv<<<dim3(D_ / 128, S_ / 128, B_), dim3(256), 0, stream>>>(attn, vt, out);
}

// Round 3
// 373.779 us; speedup vs baseline: 1.1536x; 1.1536x over previous
//
#include <hip/hip_runtime.h>
#include <stdint.h>

typedef unsigned short u16;
typedef short bf16x8 __attribute__((ext_vector_type(8)));
typedef float f32x4 __attribute__((ext_vector_type(4)));

#define B_   4
#define S_   2048
#define D_   1024
#define ND3  3072

// RNE float->bf16
__device__ __forceinline__ u16 f2bf(float x) {
    union { float f; uint32_t u; } v; v.f = x;
    uint32_t r = v.u + 0x7fffu + ((v.u >> 16) & 1u);
    return (u16)(r >> 16);
}
__device__ __forceinline__ float bf2f(u16 h) {
    union { uint32_t u; float f; } v; v.u = ((uint32_t)h) << 16;
    return v.f;
}

__device__ __forceinline__ void gload_lds16(const u16* g, u16* l) {
    __builtin_amdgcn_global_load_lds((const __attribute__((address_space(1))) void*)g,
                                     (__attribute__((address_space(3))) void*)l, 16, 0, 0);
}

// ================= 256x256 8-phase bf16 GEMM core =================
// A [M][K] row-major, Bt [N][K] row-major; K%64==0, K/64>=2.
// 512 threads = 8 waves as 2(Mrow) x 4(Ncol); per-wave output 128x64.
// LDS 128KB: A-ring 4 slots x 16KB + B-ring 4 slots x 16KB.
// Half-tile = all 256 rows x 32 k (16KB); slot = (2*ktile + khalf)&3.
// Swizzle (T2): logical (row, chunk) stored at chunk^(row&3); applied on the
// global SOURCE address for global_load_lds (linear dest) and on ds_read.
__device__ __forceinline__ void gemm256(const u16* __restrict__ A, int lda,
                                        const u16* __restrict__ Bt, int ldb,
                                        int K, int rowbase, int colbase,
                                        u16* ldsA, u16* ldsB,
                                        f32x4 (&acc)[8][4])
{
    const int tid  = threadIdx.x;
    const int lane = tid & 63;
    const int w    = tid >> 6;
    const int wr   = w >> 2, wc = w & 3;
    const int NT   = K >> 6;

    // staging: thread linear index i in [0,1024): row = i>>2, chunk' = i&3,
    // source chunk = chunk' ^ (row&3). i = tid (load 0), tid+512 (load 1).
    const int r0 = tid >> 2;
    const int c0 = (((tid & 3) ^ (r0 & 3)) << 3);
    const u16* Asrc0 = A  + (size_t)(rowbase + r0)       * lda + c0;
    const u16* Asrc1 = A  + (size_t)(rowbase + r0 + 128) * lda + c0;
    const u16* Bsrc0 = Bt + (size_t)(colbase + r0)       * ldb + c0;
    const u16* Bsrc1 = Bt + (size_t)(colbase + r0 + 128) * ldb + c0;
    const int dst0 = tid << 3;            // u16 units
    const int dst1 = 4096 + (tid << 3);

    // ds_read per-lane: row = fragbase + (lane&15); chunk = (lane>>4) ^ (row&3)
    // row&3 == lane&3 (fragbase multiple of 16)
    const int rd_lane = ((lane & 15) << 5) + ((((lane >> 4) ^ lane) & 3) << 3);
    const int wrOff = wr << 12;           // wr*128 rows * 32 u16/row
    const int wcOff = wc << 11;           // wc*64  rows * 32 u16/row

#define ISSUE_A(kt, kh) { int sl_ = ((2*(kt)+(kh)) & 3) << 13; int ko_ = ((kt) << 6) + ((kh) << 5); \
    gload_lds16(Asrc0 + ko_, ldsA + sl_ + dst0); gload_lds16(Asrc1 + ko_, ldsA + sl_ + dst1); }
#define ISSUE_B(kt, kh) { int sl_ = ((2*(kt)+(kh)) & 3) << 13; int ko_ = ((kt) << 6) + ((kh) << 5); \
    gload_lds16(Bsrc0 + ko_, ldsB + sl_ + dst0); gload_lds16(Bsrc1 + ko_, ldsB + sl_ + dst1); }

    // prologue: issue halves 0..6 (tile0 complete + tile1 A0,B0,A1)
    ISSUE_A(0,0) ISSUE_B(0,0) ISSUE_A(0,1) ISSUE_B(0,1)
    ISSUE_A(1,0) ISSUE_B(1,0) ISSUE_A(1,1)
    asm volatile("s_waitcnt vmcnt(6)" ::: "memory");   // tile0 (oldest 4 halves) landed
    __builtin_amdgcn_s_barrier();

    bf16x8 af[4], bf[4];

#define PHASE(jj, mh, ks, READB) { \
        int sOff_ = ((2*t + (ks)) & 3) << 13; \
        _Pragma("unroll") for (int mq = 0; mq < 4; ++mq) \
            af[mq] = *(const bf16x8*)(ldsA + sOff_ + wrOff + ((mh) << 11) + (mq << 9) + rd_lane); \
        if (READB) { _Pragma("unroll") for (int n = 0; n < 4; ++n) \
            bf[n] = *(const bf16x8*)(ldsB + sOff_ + wcOff + (n << 9) + rd_lane); } \
        __builtin_amdgcn_s_barrier(); \
        { int h_ = 4*t + (jj) + 7; \
          if (h_ < 4*NT) { int th_ = h_ >> 2; int sq_ = h_ & 3; int kh_ = sq_ >> 1; \
            int sl_ = ((2*th_ + kh_) & 3) << 13; int ko_ = (th_ << 6) + (kh_ << 5); \
            if ((sq_ & 1) == 0) { gload_lds16(Asrc0 + ko_, ldsA + sl_ + dst0); \
                                  gload_lds16(Asrc1 + ko_, ldsA + sl_ + dst1); } \
            else                { gload_lds16(Bsrc0 + ko_, ldsB + sl_ + dst0); \
                                  gload_lds16(Bsrc1 + ko_, ldsB + sl_ + dst1); } } } \
        asm volatile("s_waitcnt lgkmcnt(0)" ::: "memory"); \
        __builtin_amdgcn_sched_barrier(0); \
        __builtin_amdgcn_s_setprio(1); \
        _Pragma("unroll") for (int mq = 0; mq < 4; ++mq) \
        _Pragma("unroll") for (int n = 0; n < 4; ++n) \
            acc[(mh)*4+mq][n] = __builtin_amdgcn_mfma_f32_16x16x32_bf16(af[mq], bf[n], acc[(mh)*4+mq][n], 0, 0, 0); \
        __builtin_amdgcn_s_setprio(0); \
        if ((jj) == 3) { if (t < NT-2) asm volatile("s_waitcnt vmcnt(6)" ::: "memory"); \
                         else          asm volatile("s_waitcnt vmcnt(0)" ::: "memory"); } \
        __builtin_amdgcn_s_barrier(); }

    for (int t = 0; t < NT; ++t) {
        PHASE(0, 0, 0, 1)
        PHASE(1, 1, 0, 0)
        PHASE(2, 0, 1, 1)
        PHASE(3, 1, 1, 0)
    }
#undef PHASE
#undef ISSUE_A
#undef ISSUE_B
}

// ---------------- stage 0a: fp32 -> (hi, lo) bf16 split ----------------
__global__ __launch_bounds__(256) void k_split_f32(const float* __restrict__ in,
                                                   u16* __restrict__ oh,
                                                   u16* __restrict__ ol, int n) {
    int i = (blockIdx.x * 256 + threadIdx.x) << 3;
    if (i >= n) return;
    float4 a = *(const float4*)(in + i);
    float4 b = *(const float4*)(in + i + 4);
    ushort4 h0, h1, l0, l1;
    h0.x = f2bf(a.x); l0.x = f2bf(a.x - bf2f(h0.x));
    h0.y = f2bf(a.y); l0.y = f2bf(a.y - bf2f(h0.y));
    h0.z = f2bf(a.z); l0.z = f2bf(a.z - bf2f(h0.z));
    h0.w = f2bf(a.w); l0.w = f2bf(a.w - bf2f(h0.w));
    h1.x = f2bf(b.x); l1.x = f2bf(b.x - bf2f(h1.x));
    h1.y = f2bf(b.y); l1.y = f2bf(b.y - bf2f(h1.y));
    h1.z = f2bf(b.z); l1.z = f2bf(b.z - bf2f(h1.z));
    h1.w = f2bf(b.w); l1.w = f2bf(b.w - bf2f(h1.w));
    *(ushort4*)(oh + i)     = h0;
    *(ushort4*)(oh + i + 4) = h1;
    *(ushort4*)(ol + i)     = l0;
    *(ushort4*)(ol + i + 4) = l1;
}

// ---------------- stage 0b: W [R][C] fp32 -> Wt hi/lo [C][R] bf16 ----------------
__global__ __launch_bounds__(256) void k_transpose_split(const float* __restrict__ W,
                                                         u16* __restrict__ Wth,
                                                         u16* __restrict__ Wtl, int R, int C) {
    __shared__ float t[32][33];
    int tx = threadIdx.x & 31, ty = threadIdx.x >> 5;
    int c0 = blockIdx.x << 5, r0 = blockIdx.y << 5;
#pragma unroll
    for (int i = 0; i < 4; ++i) {
        int r = (i << 3) + ty;
        t[r][tx] = W[(size_t)(r0 + r) * C + c0 + tx];
    }
    __syncthreads();
#pragma unroll
    for (int i = 0; i < 4; ++i) {
        int r = (i << 3) + ty;
        float w = t[tx][r];
        u16 h = f2bf(w);
        Wth[(size_t)(c0 + r) * R + r0 + tx] = h;
        Wtl[(size_t)(c0 + r) * R + r0 + tx] = f2bf(w - bf2f(h));
    }
}

// ---------------- stage 1: QKV (hi/lo 3-seg); split-store q,k; v transposed ----------------
__global__ __launch_bounds__(512, 2) void k_qkv(const u16* __restrict__ xh,
                                                const u16* __restrict__ xl,
                                                const u16* __restrict__ wth,
                                                const u16* __restrict__ wtl,
                                                const float* __restrict__ bias,
                                                u16* __restrict__ qhi, u16* __restrict__ qlo,
                                                u16* __restrict__ khi, u16* __restrict__ klo,
                                                u16* __restrict__ vt) {
    __shared__ u16 lds[65536];
    f32x4 acc[8][4];
    f32x4 z = {0.f, 0.f, 0.f, 0.f};
#pragma unroll
    for (int m = 0; m < 8; ++m)
#pragma unroll
        for (int n = 0; n < 4; ++n) acc[m][n] = z;

    const int rowbase = blockIdx.y << 8;
    const int colbase = blockIdx.x << 8;
    gemm256(xh, D_, wth, D_, D_, rowbase, colbase, lds, lds + 32768, acc);
    gemm256(xh, D_, wtl, D_, D_, rowbase, colbase, lds, lds + 32768, acc);
    gemm256(xl, D_, wth, D_, D_, rowbase, colbase, lds, lds + 32768, acc);

    const int lane = threadIdx.x & 63;
    const int w = threadIdx.x >> 6;
    const int wr = w >> 2, wc = w & 3;
    const int region = colbase >> 10;   // 0=q, 1=k, 2=v (256 | 1024)
#pragma unroll
    for (int m = 0; m < 8; ++m) {
        int gr0 = rowbase + wr * 128 + m * 16 + ((lane >> 4) << 2);
#pragma unroll
        for (int n = 0; n < 4; ++n) {
            int gc = colbase + wc * 64 + n * 16 + (lane & 15);
            float bv = bias[gc];
            if (region == 0) {
#pragma unroll
                for (int r = 0; r < 4; ++r) {
                    float val = acc[m][n][r] + bv;
                    u16 h = f2bf(val);
                    size_t idx = (size_t)(gr0 + r) * D_ + gc;
                    qhi[idx] = h;
                    qlo[idx] = f2bf(val - bf2f(h));
                }
            } else if (region == 1) {
                int c = gc - 1024;
#pragma unroll
                for (int r = 0; r < 4; ++r) {
                    float val = acc[m][n][r] + bv;
                    u16 h = f2bf(val);
                    size_t idx = (size_t)(gr0 + r) * D_ + c;
                    khi[idx] = h;
                    klo[idx] = f2bf(val - bf2f(h));
                }
            } else {
                int d  = gc - 2048;
                int b  = gr0 >> 11;
                int t0 = gr0 & 2047;
                size_t base = (((size_t)b << 10) + d) * (size_t)S_ + t0;
#pragma unroll
                for (int r = 0; r < 4; ++r)
                    vt[base + r] = f2bf(acc[m][n][r] + bv);
            }
        }
    }
}

// ---------------- stage 2: attn = sigmoid(32 * q @ k^T) (3-seg), bf16 ----------------
__global__ __launch_bounds__(512, 2) void k_scores(const u16* __restrict__ qhi,
                                                   const u16* __restrict__ qlo,
                                                   const u16* __restrict__ khi,
                                                   const u16* __restrict__ klo,
                                                   u16* __restrict__ attn) {
    __shared__ u16 lds[65536];
    f32x4 acc[8][4];
    f32x4 z = {0.f, 0.f, 0.f, 0.f};
#pragma unroll
    for (int m = 0; m < 8; ++m)
#pragma unroll
        for (int n = 0; n < 4; ++n) acc[m][n] = z;

    const int b = blockIdx.z;
    const size_t boff = (size_t)b * S_ * D_;
    u16* att = attn + (size_t)b * S_ * S_;
    const int rowbase = blockIdx.y << 8, colbase = blockIdx.x << 8;
    gemm256(qhi + boff, D_, khi + boff, D_, D_, rowbase, colbase, lds, lds + 32768, acc);
    gemm256(qhi + boff, D_, klo + boff, D_, D_, rowbase, colbase, lds, lds + 32768, acc);
    gemm256(qlo + boff, D_, khi + boff, D_, D_, rowbase, colbase, lds, lds + 32768, acc);

    const int lane = threadIdx.x & 63;
    const int w = threadIdx.x >> 6;
    const int wr = w >> 2, wc = w & 3;
#pragma unroll
    for (int m = 0; m < 8; ++m) {
        int gr0 = rowbase + wr * 128 + m * 16 + ((lane >> 4) << 2);
#pragma unroll
        for (int n = 0; n < 4; ++n) {
            int gc = colbase + wc * 64 + n * 16 + (lane & 15);
#pragma unroll
            for (int r = 0; r < 4; ++r) {
                float sv = acc[m][n][r] * 32.0f;
                float sg = 1.0f / (1.0f + __expf(-sv));
                att[(size_t)(gr0 + r) * S_ + gc] = f2bf(sg);
            }
        }
    }
}

// ---------------- stage 3: out = attn @ v  (Bt = v^T [D][S]) ----------------
__global__ __launch_bounds__(512, 2) void k_pv(const u16* __restrict__ attn,
                                               const u16* __restrict__ vt,
                                               float* __restrict__ out) {
    __shared__ u16 lds[65536];
    f32x4 acc[8][4];
    f32x4 z = {0.f, 0.f, 0.f, 0.f};
#pragma unroll
    for (int m = 0; m < 8; ++m)
#pragma unroll
        for (int n = 0; n < 4; ++n) acc[m][n] = z;

    const int b = blockIdx.z;
    const u16* Aa = attn + (size_t)b * S_ * S_;
    const u16* Bv = vt   + (size_t)b * D_ * S_;
    float* ob     = out  + (size_t)b * S_ * D_;
    const int rowbase = blockIdx.y << 8, colbase = blockIdx.x << 8;
    gemm256(Aa, S_, Bv, S_, S_, rowbase, colbase, lds, lds + 32768, acc);

    const int lane = threadIdx.x & 63;
    const int w = threadIdx.x >> 6;
    const int wr = w >> 2, wc = w & 3;
#pragma unroll
    for (int m = 0; m < 8; ++m) {
        int gr0 = rowbase + wr * 128 + m * 16 + ((lane >> 4) << 2);
#pragma unroll
        for (int n = 0; n < 4; ++n) {
            int gc = colbase + wc * 64 + n * 16 + (lane & 15);
#pragma unroll
            for (int r = 0; r < 4; ++r)
                ob[(size_t)(gr0 + r) * D_ + gc] = acc[m][n][r];
        }
    }
}

extern "C" void kernel_launch(void* const* d_in, const int* in_sizes, int n_in,
                              void* d_out, int out_size, void* d_ws, size_t ws_size,
                              hipStream_t stream) {
    const float* x    = (const float*)d_in[0];
    const float* wqkv = (const float*)d_in[1];
    const float* bias = (const float*)d_in[2];
    float* out = (float*)d_out;

    const size_t MB = 1048576;
    uint8_t* ws = (uint8_t*)d_ws;
    u16* xh   = (u16*)(ws);              // [8192][1024] bf16   16 MB
    u16* xl   = (u16*)(ws + 16 * MB);    // 16 MB
    u16* wth  = (u16*)(ws + 32 * MB);    // [3072][1024] bf16    6 MB
    u16* wtl  = (u16*)(ws + 38 * MB);    //  6 MB
    u16* qh   = (u16*)(ws + 44 * MB);    // [B][S][D] bf16      16 MB
    u16* ql   = (u16*)(ws + 60 * MB);    // 16 MB
    u16* kh   = (u16*)(ws + 76 * MB);    // 16 MB
    u16* kl   = (u16*)(ws + 92 * MB);    // 16 MB
    u16* vt   = (u16*)(ws + 108 * MB);   // [B][D][S] bf16      16 MB (ends 124 MB)
    u16* attn = (u16*)(ws);              // [B][S][S] bf16 32 MB — aliases xh/xl (dead after QKV)

    k_split_f32<<<dim3(4096), dim3(256), 0, stream>>>(x, xh, xl, B_ * S_ * D_);
    k_transpose_split<<<dim3(ND3 / 32, D_ / 32), dim3(256), 0, stream>>>(wqkv, wth, wtl, D_, ND3);
    k_qkv<<<dim3(ND3 / 256, (B_ * S_) / 256), dim3(512), 0, stream>>>(xh, xl, wth, wtl, bias,
                                                                      qh, ql, kh, kl, vt);
    k_scores<<<dim3(S_ / 256, S_ / 256, B_), dim3(512), 0, stream>>>(qh, ql, kh, kl, attn);
    k_pv<<<dim3(D_ / 256, S_ / 256, B_), dim3(512), 0, stream>>>(attn, vt, out);
}

// Round 4
// 370.526 us; speedup vs baseline: 1.1637x; 1.0088x over previous
//
#include <hip/hip_runtime.h>
#include <stdint.h>

typedef unsigned short u16;
typedef short bf16x8 __attribute__((ext_vector_type(8)));
typedef float f32x4 __attribute__((ext_vector_type(4)));

#define B_   4
#define S_   2048
#define D_   1024
#define ND3  3072

// RNE float->bf16
__device__ __forceinline__ u16 f2bf(float x) {
    union { float f; uint32_t u; } v; v.f = x;
    uint32_t r = v.u + 0x7fffu + ((v.u >> 16) & 1u);
    return (u16)(r >> 16);
}
__device__ __forceinline__ float bf2f(u16 h) {
    union { uint32_t u; float f; } v; v.u = ((uint32_t)h) << 16;
    return v.f;
}

__device__ __forceinline__ void gload_lds16(const u16* g, u16* l) {
    __builtin_amdgcn_global_load_lds((const __attribute__((address_space(1))) void*)g,
                                     (__attribute__((address_space(3))) void*)l, 16, 0, 0);
}

// ================= 256x256 8-phase bf16 GEMM core (multi-segment fused) =================
// Computes acc += sum_s A_s @ B_s^T over NSEG segments, each K = NTSEG*64.
// A_s [M][K] row-major, B_s [N][K] row-major. 512 threads = 8 waves (2Mrow x 4Ncol),
// per-wave output 128x64. LDS 128KB: A-ring 4 x 16KB + B-ring 4 x 16KB.
// Half-tile = 256 rows x 32 k; ring slot = (2*T + kh) & 3 (T = global tile).
// Swizzle: logical (row, chunk16B c in 0..3) stored at c ^ ((row>>1)&3).
//   slot16B = 4*(row&1) + (c ^ ((row>>1)&3)) -> 8 consecutive rows cover all 8
//   slots of the 128B bank line => conflict-free ds_read_b128.
// Applied on the global SOURCE address (linear LDS dest for global_load_lds)
// and identically on the ds_read address (same involution both sides).
template<int NSEG, int NTSEG>
__device__ __forceinline__ void gemm256(const u16* __restrict__ a0, const u16* __restrict__ b0,
                                        const u16* __restrict__ a1, const u16* __restrict__ b1,
                                        const u16* __restrict__ a2, const u16* __restrict__ b2,
                                        int lda, int ldb, int rowbase, int colbase,
                                        u16* ldsA, u16* ldsB, f32x4 (&acc)[8][4])
{
    const int NTOT = NSEG * NTSEG;
    const int tid  = threadIdx.x;
    const int lane = tid & 63;
    const int w    = tid >> 6;
    const int wr   = w >> 2, wc = w & 3;

    // staging: thread tid -> row r0 = tid>>2, physical chunk tid&3 (linear dest),
    // global source chunk = (tid&3) ^ ((r0>>1)&3)
    const int r0 = tid >> 2;
    const int c0 = (((tid & 3) ^ ((tid >> 3) & 3)) << 3);
    const size_t offA0 = (size_t)(rowbase + r0) * lda + c0;
    const size_t offA1 = offA0 + (size_t)128 * lda;
    const size_t offB0 = (size_t)(colbase + r0) * ldb + c0;
    const size_t offB1 = offB0 + (size_t)128 * ldb;
    const int dst0 = tid << 3;            // u16 units (16B per thread, linear)
    const int dst1 = 4096 + (tid << 3);

    // ds_read per-lane: row = fragbase + (lane&15), logical chunk = lane>>4,
    // physical chunk = (lane>>4) ^ ((row>>1)&3) = (lane>>4) ^ ((lane>>1)&3)
    const int rd_lane = ((lane & 15) << 5) + ((((lane >> 4) ^ (lane >> 1)) & 3) << 3);
    const int wrOff = wr << 12;           // wr*128 rows * 32 u16/row
    const int wcOff = wc << 11;           // wc*64  rows * 32 u16/row

#define ISSUE(qv) do { int q_ = (qv); \
    if (q_ < 4 * NTOT) { \
        const u16* Ab_; const u16* Bb_; int ql_; \
        if (NSEG == 1 || q_ < 4 * NTSEG) { Ab_ = a0; Bb_ = b0; ql_ = q_; } \
        else if (q_ < 8 * NTSEG)         { Ab_ = a1; Bb_ = b1; ql_ = q_ - 4 * NTSEG; } \
        else                             { Ab_ = a2; Bb_ = b2; ql_ = q_ - 8 * NTSEG; } \
        int Tq_ = ql_ >> 2, r_ = ql_ & 3, kh_ = r_ >> 1; \
        int sl_ = ((2 * Tq_ + kh_) & 3) << 13; \
        size_t ko_ = ((size_t)Tq_ << 6) + (kh_ << 5); \
        if ((r_ & 1) == 0) { gload_lds16(Ab_ + offA0 + ko_, ldsA + sl_ + dst0); \
                             gload_lds16(Ab_ + offA1 + ko_, ldsA + sl_ + dst1); } \
        else               { gload_lds16(Bb_ + offB0 + ko_, ldsB + sl_ + dst0); \
                             gload_lds16(Bb_ + offB1 + ko_, ldsB + sl_ + dst1); } \
    } } while (0)

    // prologue: issue quarters 0..6 (A00,B00,A01,B01,A10,B10,A11)
    ISSUE(0); ISSUE(1); ISSUE(2); ISSUE(3); ISSUE(4); ISSUE(5); ISSUE(6);
    asm volatile("s_waitcnt vmcnt(6)" ::: "memory");   // tile0 (oldest 4 halves) landed
    __builtin_amdgcn_s_barrier();

    bf16x8 af[4], bf[4];

#define PHASE(jj, mh, ks) { \
        int sOff_ = ((2 * T + (ks)) & 3) << 13; \
        _Pragma("unroll") for (int mq = 0; mq < 4; ++mq) \
            af[mq] = *(const bf16x8*)(ldsA + sOff_ + wrOff + ((mh) << 11) + (mq << 9) + rd_lane); \
        if ((jj) == 0 || (jj) == 2) { _Pragma("unroll") for (int n = 0; n < 4; ++n) \
            bf[n] = *(const bf16x8*)(ldsB + sOff_ + wcOff + (n << 9) + rd_lane); } \
        __builtin_amdgcn_s_barrier(); \
        ISSUE(4 * T + (jj) + 7); \
        asm volatile("s_waitcnt lgkmcnt(0)" ::: "memory"); \
        __builtin_amdgcn_sched_barrier(0); \
        __builtin_amdgcn_s_setprio(1); \
        _Pragma("unroll") for (int mq = 0; mq < 4; ++mq) \
        _Pragma("unroll") for (int n = 0; n < 4; ++n) \
            acc[(mh) * 4 + mq][n] = __builtin_amdgcn_mfma_f32_16x16x32_bf16(af[mq], bf[n], acc[(mh) * 4 + mq][n], 0, 0, 0); \
        __builtin_amdgcn_s_setprio(0); \
        if ((jj) == 3) { if (T < NTOT - 2)       asm volatile("s_waitcnt vmcnt(6)" ::: "memory"); \
                         else if (T == NTOT - 2) asm volatile("s_waitcnt vmcnt(0)" ::: "memory"); } \
        __builtin_amdgcn_s_barrier(); }

    for (int T = 0; T < NTOT; ++T) {
        PHASE(0, 0, 0)
        PHASE(1, 1, 0)
        PHASE(2, 0, 1)
        PHASE(3, 1, 1)
    }
#undef PHASE
#undef ISSUE
}

// ---------------- stage 0a: fp32 -> (hi, lo) bf16 split ----------------
__global__ __launch_bounds__(256) void k_split_f32(const float* __restrict__ in,
                                                   u16* __restrict__ oh,
                                                   u16* __restrict__ ol, int n) {
    int i = (blockIdx.x * 256 + threadIdx.x) << 3;
    if (i >= n) return;
    float4 a = *(const float4*)(in + i);
    float4 b = *(const float4*)(in + i + 4);
    ushort4 h0, h1, l0, l1;
    h0.x = f2bf(a.x); l0.x = f2bf(a.x - bf2f(h0.x));
    h0.y = f2bf(a.y); l0.y = f2bf(a.y - bf2f(h0.y));
    h0.z = f2bf(a.z); l0.z = f2bf(a.z - bf2f(h0.z));
    h0.w = f2bf(a.w); l0.w = f2bf(a.w - bf2f(h0.w));
    h1.x = f2bf(b.x); l1.x = f2bf(b.x - bf2f(h1.x));
    h1.y = f2bf(b.y); l1.y = f2bf(b.y - bf2f(h1.y));
    h1.z = f2bf(b.z); l1.z = f2bf(b.z - bf2f(h1.z));
    h1.w = f2bf(b.w); l1.w = f2bf(b.w - bf2f(h1.w));
    *(ushort4*)(oh + i)     = h0;
    *(ushort4*)(oh + i + 4) = h1;
    *(ushort4*)(ol + i)     = l0;
    *(ushort4*)(ol + i + 4) = l1;
}

// ---------------- stage 0b: W [R][C] fp32 -> Wt hi/lo [C][R] bf16 ----------------
__global__ __launch_bounds__(256) void k_transpose_split(const float* __restrict__ W,
                                                         u16* __restrict__ Wth,
                                                         u16* __restrict__ Wtl, int R, int C) {
    __shared__ float t[32][33];
    int tx = threadIdx.x & 31, ty = threadIdx.x >> 5;
    int c0 = blockIdx.x << 5, r0 = blockIdx.y << 5;
#pragma unroll
    for (int i = 0; i < 4; ++i) {
        int r = (i << 3) + ty;
        t[r][tx] = W[(size_t)(r0 + r) * C + c0 + tx];
    }
    __syncthreads();
#pragma unroll
    for (int i = 0; i < 4; ++i) {
        int r = (i << 3) + ty;
        float w = t[tx][r];
        u16 h = f2bf(w);
        Wth[(size_t)(c0 + r) * R + r0 + tx] = h;
        Wtl[(size_t)(c0 + r) * R + r0 + tx] = f2bf(w - bf2f(h));
    }
}

// ---------------- stage 1: QKV (hi/lo 3-seg fused); split-store q,k; v transposed ----------------
__global__ __launch_bounds__(512, 2) void k_qkv(const u16* __restrict__ xh,
                                                const u16* __restrict__ xl,
                                                const u16* __restrict__ wth,
                                                const u16* __restrict__ wtl,
                                                const float* __restrict__ bias,
                                                u16* __restrict__ qhi, u16* __restrict__ qlo,
                                                u16* __restrict__ khi, u16* __restrict__ klo,
                                                u16* __restrict__ vt) {
    __shared__ u16 lds[65536];
    f32x4 acc[8][4];
    f32x4 z = {0.f, 0.f, 0.f, 0.f};
#pragma unroll
    for (int m = 0; m < 8; ++m)
#pragma unroll
        for (int n = 0; n < 4; ++n) acc[m][n] = z;

    const int rowbase = blockIdx.y << 8;
    const int colbase = blockIdx.x << 8;
    gemm256<3, 16>(xh, wth, xh, wtl, xl, wth, D_, D_, rowbase, colbase,
                   lds, lds + 32768, acc);

    const int lane = threadIdx.x & 63;
    const int w = threadIdx.x >> 6;
    const int wr = w >> 2, wc = w & 3;
    const int region = colbase >> 10;   // 0=q, 1=k, 2=v (256 | 1024)
#pragma unroll
    for (int m = 0; m < 8; ++m) {
        int gr0 = rowbase + wr * 128 + m * 16 + ((lane >> 4) << 2);
#pragma unroll
        for (int n = 0; n < 4; ++n) {
            int gc = colbase + wc * 64 + n * 16 + (lane & 15);
            float bv = bias[gc];
            if (region == 0) {
#pragma unroll
                for (int r = 0; r < 4; ++r) {
                    float val = acc[m][n][r] + bv;
                    u16 h = f2bf(val);
                    size_t idx = (size_t)(gr0 + r) * D_ + gc;
                    qhi[idx] = h;
                    qlo[idx] = f2bf(val - bf2f(h));
                }
            } else if (region == 1) {
                int c = gc - 1024;
#pragma unroll
                for (int r = 0; r < 4; ++r) {
                    float val = acc[m][n][r] + bv;
                    u16 h = f2bf(val);
                    size_t idx = (size_t)(gr0 + r) * D_ + c;
                    khi[idx] = h;
                    klo[idx] = f2bf(val - bf2f(h));
                }
            } else {
                int d  = gc - 2048;
                int b  = gr0 >> 11;
                int t0 = gr0 & 2047;
                size_t base = (((size_t)b << 10) + d) * (size_t)S_ + t0;
#pragma unroll
                for (int r = 0; r < 4; ++r)
                    vt[base + r] = f2bf(acc[m][n][r] + bv);
            }
        }
    }
}

// ---------------- stage 2: attn = sigmoid(32 * q @ k^T) (3-seg fused), bf16 ----------------
__global__ __launch_bounds__(512, 2) void k_scores(const u16* __restrict__ qhi,
                                                   const u16* __restrict__ qlo,
                                                   const u16* __restrict__ khi,
                                                   const u16* __restrict__ klo,
                                                   u16* __restrict__ attn) {
    __shared__ u16 lds[65536];
    f32x4 acc[8][4];
    f32x4 z = {0.f, 0.f, 0.f, 0.f};
#pragma unroll
    for (int m = 0; m < 8; ++m)
#pragma unroll
        for (int n = 0; n < 4; ++n) acc[m][n] = z;

    const int b = blockIdx.z;
    const size_t boff = (size_t)b * S_ * D_;
    u16* att = attn + (size_t)b * S_ * S_;
    const int rowbase = blockIdx.y << 8, colbase = blockIdx.x << 8;
    gemm256<3, 16>(qhi + boff, khi + boff, qhi + boff, klo + boff, qlo + boff, khi + boff,
                   D_, D_, rowbase, colbase, lds, lds + 32768, acc);

    const int lane = threadIdx.x & 63;
    const int w = threadIdx.x >> 6;
    const int wr = w >> 2, wc = w & 3;
#pragma unroll
    for (int m = 0; m < 8; ++m) {
        int gr0 = rowbase + wr * 128 + m * 16 + ((lane >> 4) << 2);
#pragma unroll
        for (int n = 0; n < 4; ++n) {
            int gc = colbase + wc * 64 + n * 16 + (lane & 15);
#pragma unroll
            for (int r = 0; r < 4; ++r) {
                float sv = acc[m][n][r] * 32.0f;
                float sg = 1.0f / (1.0f + __expf(-sv));
                att[(size_t)(gr0 + r) * S_ + gc] = f2bf(sg);
            }
        }
    }
}

// ---------------- stage 3: out = attn @ v  (Bt = v^T [D][S]) ----------------
__global__ __launch_bounds__(512, 2) void k_pv(const u16* __restrict__ attn,
                                               const u16* __restrict__ vt,
                                               float* __restrict__ out) {
    __shared__ u16 lds[65536];
    f32x4 acc[8][4];
    f32x4 z = {0.f, 0.f, 0.f, 0.f};
#pragma unroll
    for (int m = 0; m < 8; ++m)
#pragma unroll
        for (int n = 0; n < 4; ++n) acc[m][n] = z;

    const int b = blockIdx.z;
    const u16* Aa = attn + (size_t)b * S_ * S_;
    const u16* Bv = vt   + (size_t)b * D_ * S_;
    float* ob     = out  + (size_t)b * S_ * D_;
    const int rowbase = blockIdx.y << 8, colbase = blockIdx.x << 8;
    gemm256<1, 32>(Aa, Bv, Aa, Bv, Aa, Bv, S_, S_, rowbase, colbase,
                   lds, lds + 32768, acc);

    const int lane = threadIdx.x & 63;
    const int w = threadIdx.x >> 6;
    const int wr = w >> 2, wc = w & 3;
#pragma unroll
    for (int m = 0; m < 8; ++m) {
        int gr0 = rowbase + wr * 128 + m * 16 + ((lane >> 4) << 2);
#pragma unroll
        for (int n = 0; n < 4; ++n) {
            int gc = colbase + wc * 64 + n * 16 + (lane & 15);
#pragma unroll
            for (int r = 0; r < 4; ++r)
                ob[(size_t)(gr0 + r) * D_ + gc] = acc[m][n][r];
        }
    }
}

extern "C" void kernel_launch(void* const* d_in, const int* in_sizes, int n_in,
                              void* d_out, int out_size, void* d_ws, size_t ws_size,
                              hipStream_t stream) {
    const float* x    = (const float*)d_in[0];
    const float* wqkv = (const float*)d_in[1];
    const float* bias = (const float*)d_in[2];
    float* out = (float*)d_out;

    const size_t MB = 1048576;
    uint8_t* ws = (uint8_t*)d_ws;
    u16* xh   = (u16*)(ws);              // [8192][1024] bf16   16 MB
    u16* xl   = (u16*)(ws + 16 * MB);    // 16 MB
    u16* wth  = (u16*)(ws + 32 * MB);    // [3072][1024] bf16    6 MB
    u16* wtl  = (u16*)(ws + 38 * MB);    //  6 MB
    u16* qh   = (u16*)(ws + 44 * MB);    // [B][S][D] bf16      16 MB
    u16* ql   = (u16*)(ws + 60 * MB);    // 16 MB
    u16* kh   = (u16*)(ws + 76 * MB);    // 16 MB
    u16* kl   = (u16*)(ws + 92 * MB);    // 16 MB
    u16* vt   = (u16*)(ws + 108 * MB);   // [B][D][S] bf16      16 MB (ends 124 MB)
    u16* attn = (u16*)(ws);              // [B][S][S] bf16 32 MB — aliases xh/xl (dead after QKV)

    k_split_f32<<<dim3(4096), dim3(256), 0, stream>>>(x, xh, xl, B_ * S_ * D_);
    k_transpose_split<<<dim3(ND3 / 32, D_ / 32), dim3(256), 0, stream>>>(wqkv, wth, wtl, D_, ND3);
    k_qkv<<<dim3(ND3 / 256, (B_ * S_) / 256), dim3(512), 0, stream>>>(xh, xl, wth, wtl, bias,
                                                                      qh, ql, kh, kl, vt);
    k_scores<<<dim3(S_ / 256, S_ / 256, B_), dim3(512), 0, stream>>>(qh, ql, kh, kl, attn);
    k_pv<<<dim3(D_ / 256, S_ / 256, B_), dim3(512), 0, stream>>>(attn, vt, out);
}